// Round 1
// baseline (748.111 us; speedup 1.0000x reference)
//
#include <hip/hip_runtime.h>

#define B 4
#define C 256
#define K 64
#define NN 4096      // H*W = 64*64
#define NCH 16       // n-chunks for M-step partials

// workspace layout (floats)
#define OFF_XT   0                          // B*NN*C = 4194304
#define OFF_MU   4194304                    // B*C*K  = 65536
#define OFF_SIG  4259840                    // 3*B*NN*K = 3145728
#define OFF_TP   7405568                    // B*NCH*K*C = 1048576
#define OFF_P    8454144                    // 3*B*K*C = 196608
// total floats = 8650752  (~34.6 MB)

// ---------------- transpose x (b,c,n) -> xT (b,n,c) ----------------
__global__ void k_transpose(const float* __restrict__ x, float* __restrict__ xT) {
    __shared__ float tile[32][33];
    int b = blockIdx.z, c0 = blockIdx.y * 32, n0 = blockIdx.x * 32;
    int tx = threadIdx.x, ty = threadIdx.y; // (32,8)
    #pragma unroll
    for (int j = 0; j < 4; j++) {
        int c = c0 + ty + j * 8;
        tile[ty + j * 8][tx] = x[((size_t)(b * C + c)) * NN + n0 + tx];
    }
    __syncthreads();
    #pragma unroll
    for (int j = 0; j < 4; j++) {
        int n = n0 + ty + j * 8;
        xT[((size_t)(b * NN + n)) * C + c0 + tx] = tile[tx][ty + j * 8];
    }
}

// ---------------- init mu = broadcast mu0 ----------------
__global__ void k_initmu(const float* __restrict__ mu0, float* __restrict__ mu) {
    int i = blockIdx.x * 256 + threadIdx.x;
    mu[i] = mu0[i & (C * K - 1)];
}

// ---------------- E-step: T = xT*mu, softmax over k, weight by cnt ----------------
// grid (NN/64, B), block 256.  sig[b][n][k] = softmax_k(T)[n][k] * cnt(n)
__global__ void k_estep(const float* __restrict__ xT, const float* __restrict__ mu,
                        float* __restrict__ sig, int p) {
    __shared__ __align__(16) float ms[64][64];   // [c][k]
    __shared__ __align__(16) float xs[64][68];   // [c][n_local]
    int b = blockIdx.y;
    int n0 = blockIdx.x * 64;
    int tid = threadIdx.x;
    int kq = tid & 15, rq = tid >> 4;
    float acc[4][4] = {}; // [rr][kk]
    for (int cc = 0; cc < 4; cc++) {
        int c0 = cc * 64;
        for (int t = tid; t < 4096; t += 256) {
            int i = t >> 6, k = t & 63;
            ms[i][k] = mu[((size_t)(b * C + c0 + i)) * K + k];
        }
        for (int t = tid; t < 4096; t += 256) {
            int i = t & 63, nl = t >> 6;
            xs[i][nl] = xT[((size_t)(b * NN + n0 + nl)) * C + c0 + i];
        }
        __syncthreads();
        #pragma unroll
        for (int i = 0; i < 64; i++) {
            float4 a4 = *(const float4*)&xs[i][rq * 4];
            float4 b4 = *(const float4*)&ms[i][kq * 4];
            float a_[4] = {a4.x, a4.y, a4.z, a4.w};
            float b_[4] = {b4.x, b4.y, b4.z, b4.w};
            #pragma unroll
            for (int rr = 0; rr < 4; rr++)
                #pragma unroll
                for (int kk = 0; kk < 4; kk++)
                    acc[rr][kk] += a_[rr] * b_[kk];
        }
        __syncthreads();
    }
    // softmax over k (64 values live in 16 consecutive lanes x 4 regs)
    #pragma unroll
    for (int rr = 0; rr < 4; rr++) {
        int n = n0 + rq * 4 + rr;
        float m = fmaxf(fmaxf(acc[rr][0], acc[rr][1]), fmaxf(acc[rr][2], acc[rr][3]));
        #pragma unroll
        for (int off = 1; off <= 8; off <<= 1) m = fmaxf(m, __shfl_xor(m, off));
        float e[4], ssum = 0.f;
        #pragma unroll
        for (int kk = 0; kk < 4; kk++) { e[kk] = expf(acc[rr][kk] - m); ssum += e[kk]; }
        #pragma unroll
        for (int off = 1; off <= 8; off <<= 1) ssum += __shfl_xor(ssum, off);
        int y = n >> 6, xc = n & 63;
        int cy = min(p, y) + min(p, 63 - y) + 1;
        int cx = min(p, xc) + min(p, 63 - xc) + 1;
        float scale = (float)(cy * cx) / ssum;
        float4 o;
        o.x = e[0] * scale; o.y = e[1] * scale; o.z = e[2] * scale; o.w = e[3] * scale;
        *(float4*)&sig[((size_t)(b * NN + n)) * K + kq * 4] = o;
    }
}

// ---------------- M-step partials: tpart[b][ch][k][c] = sum_{n in chunk} xT[n][c]*sig[n][k]
// grid (C/64, NCH, B), block 256
__global__ void k_mstep(const float* __restrict__ xT, const float* __restrict__ sig,
                        float* __restrict__ tpart) {
    __shared__ __align__(16) float ss[64][64];   // [n][k]
    __shared__ __align__(16) float xts[64][68];  // [n][c]
    int ct = blockIdx.x, ch = blockIdx.y, b = blockIdx.z;
    int tid = threadIdx.x, kq = tid & 15, cq = tid >> 4;
    int c0 = ct * 64;
    float acc[4][4] = {}; // [cc][kk]
    for (int sub = 0; sub < 4; sub++) {
        int nb = ch * 256 + sub * 64;
        for (int t = tid; t < 4096; t += 256) {
            int nl = t >> 6, k = t & 63;
            ss[nl][k] = sig[((size_t)(b * NN + nb + nl)) * K + k];
        }
        for (int t = tid; t < 4096; t += 256) {
            int nl = t >> 6, c = t & 63;
            xts[nl][c] = xT[((size_t)(b * NN + nb + nl)) * C + c0 + c];
        }
        __syncthreads();
        #pragma unroll
        for (int i = 0; i < 64; i++) {
            float4 a4 = *(const float4*)&xts[i][cq * 4];
            float4 b4 = *(const float4*)&ss[i][kq * 4];
            float a_[4] = {a4.x, a4.y, a4.z, a4.w};
            float b_[4] = {b4.x, b4.y, b4.z, b4.w};
            #pragma unroll
            for (int ccc = 0; ccc < 4; ccc++)
                #pragma unroll
                for (int kk = 0; kk < 4; kk++)
                    acc[ccc][kk] += a_[ccc] * b_[kk];
        }
        __syncthreads();
    }
    #pragma unroll
    for (int kk = 0; kk < 4; kk++) {
        float4 v = {acc[0][kk], acc[1][kk], acc[2][kk], acc[3][kk]};
        *(float4*)&tpart[((size_t)((b * NCH + ch) * K + kq * 4 + kk)) * C + c0 + cq * 4] = v;
    }
}

// ---------------- reduce partials, compute d, l2-normalize -> mu ----------------
// grid (K, B), block 256 (tid = c)
__global__ void k_norm(const float* __restrict__ sig, const float* __restrict__ tpart,
                       float* __restrict__ mu, float dconst) {
    __shared__ float red[256];
    int k = blockIdx.x, b = blockIdx.y, tid = threadIdx.x;
    float dl = 0.f;
    for (int n = tid; n < NN; n += 256) dl += sig[((size_t)(b * NN + n)) * K + k];
    red[tid] = dl; __syncthreads();
    for (int s = 128; s > 0; s >>= 1) { if (tid < s) red[tid] += red[tid + s]; __syncthreads(); }
    float d = dconst + red[0];
    __syncthreads();
    float tt = 0.f;
    #pragma unroll
    for (int ch = 0; ch < NCH; ch++)
        tt += tpart[((size_t)((b * NCH + ch) * K + k)) * C + tid];
    red[tid] = tt * tt; __syncthreads();
    for (int s = 128; s > 0; s >>= 1) { if (tid < s) red[tid] += red[tid + s]; __syncthreads(); }
    float inv = 1.f / (1e-6f * d + sqrtf(red[0]));
    mu[((size_t)(b * C + tid)) * K + k] = tt * inv;
}

// ---------------- P[s][b][k][o] = sum_i w_cat[o][s*256+i] * mu[b][i][k] ----------------
// grid (C/64, B), block 256
__global__ void k_pmat(const float* __restrict__ w_cat, const float* __restrict__ mu,
                       float* __restrict__ P, int sidx) {
    __shared__ __align__(16) float mus[64][64];  // [i][k]
    __shared__ __align__(16) float wls[64][68];  // [i][o]
    int ot = blockIdx.x, b = blockIdx.y;
    int o0 = ot * 64;
    int tid = threadIdx.x, kq = tid & 15, oq = tid >> 4;
    float acc[4][4] = {}; // [oo][kk]
    for (int cc = 0; cc < 4; cc++) {
        int c0 = cc * 64;
        for (int t = tid; t < 4096; t += 256) {
            int i = t >> 6, k = t & 63;
            mus[i][k] = mu[((size_t)(b * C + c0 + i)) * K + k];
        }
        for (int t = tid; t < 4096; t += 256) {
            int i = t & 63, ol = t >> 6;
            wls[i][ol] = w_cat[(size_t)(o0 + ol) * (3 * C) + sidx * C + c0 + i];
        }
        __syncthreads();
        #pragma unroll
        for (int i = 0; i < 64; i++) {
            float4 a4 = *(const float4*)&wls[i][oq * 4];
            float4 b4 = *(const float4*)&mus[i][kq * 4];
            float a_[4] = {a4.x, a4.y, a4.z, a4.w};
            float b_[4] = {b4.x, b4.y, b4.z, b4.w};
            #pragma unroll
            for (int oo = 0; oo < 4; oo++)
                #pragma unroll
                for (int kk = 0; kk < 4; kk++)
                    acc[oo][kk] += a_[oo] * b_[kk];
        }
        __syncthreads();
    }
    #pragma unroll
    for (int kk = 0; kk < 4; kk++) {
        float4 v = {acc[0][kk], acc[1][kk], acc[2][kk], acc[3][kk]};
        *(float4*)&P[((size_t)((sidx * B + b) * K + kq * 4 + kk)) * C + o0 + oq * 4] = v;
    }
}

// ---------------- final: out = relu(w*(sum_s sig_s * P_s^T + b_cat) + x) ----------------
// grid (NN/64, C/64, B), block 256
__global__ void k_final(const float* __restrict__ sig, const float* __restrict__ P,
                        const float* __restrict__ x, const float* __restrict__ b_cat,
                        const float* __restrict__ wscal, float* __restrict__ out) {
    __shared__ __align__(16) float st[64][68];  // [k][n_local]
    __shared__ __align__(16) float Pt[64][64];  // [k][o_local]
    int nt = blockIdx.x, ot = blockIdx.y, b = blockIdx.z;
    int n0 = nt * 64, o0 = ot * 64;
    int tid = threadIdx.x, nq = tid & 15, oq = tid >> 4;
    float acc[4][4] = {}; // [oo][nn]
    for (int s = 0; s < 3; s++) {
        for (int t = tid; t < 4096; t += 256) {
            int nl = t >> 6, k = t & 63;
            st[k][nl] = sig[((size_t)((s * B + b) * NN + n0 + nl)) * K + k];
        }
        for (int t = tid; t < 4096; t += 256) {
            int k = t >> 6, ol = t & 63;
            Pt[k][ol] = P[((size_t)((s * B + b) * K + k)) * C + o0 + ol];
        }
        __syncthreads();
        #pragma unroll
        for (int i = 0; i < 64; i++) {
            float4 a4 = *(const float4*)&st[i][nq * 4];
            float4 b4 = *(const float4*)&Pt[i][oq * 4];
            float a_[4] = {a4.x, a4.y, a4.z, a4.w};
            float b_[4] = {b4.x, b4.y, b4.z, b4.w};
            #pragma unroll
            for (int oo = 0; oo < 4; oo++)
                #pragma unroll
                for (int nn = 0; nn < 4; nn++)
                    acc[oo][nn] += b_[oo] * a_[nn];
        }
        __syncthreads();
    }
    float wv = wscal[0];
    #pragma unroll
    for (int oo = 0; oo < 4; oo++) {
        int o = o0 + oq * 4 + oo;
        float bc = b_cat[o];
        size_t base = ((size_t)(b * C + o)) * NN + n0 + nq * 4;
        float4 xv = *(const float4*)&x[base];
        float4 r;
        r.x = fmaxf((acc[oo][0] + bc) * wv + xv.x, 0.f);
        r.y = fmaxf((acc[oo][1] + bc) * wv + xv.y, 0.f);
        r.z = fmaxf((acc[oo][2] + bc) * wv + xv.z, 0.f);
        r.w = fmaxf((acc[oo][3] + bc) * wv + xv.w, 0.f);
        *(float4*)&out[base] = r;
    }
}

extern "C" void kernel_launch(void* const* d_in, const int* in_sizes, int n_in,
                              void* d_out, int out_size, void* d_ws, size_t ws_size,
                              hipStream_t stream) {
    const float* x     = (const float*)d_in[0];
    const float* mu0   = (const float*)d_in[1];
    const float* wsc   = (const float*)d_in[2];
    const float* w_cat = (const float*)d_in[3];
    const float* b_cat = (const float*)d_in[4];
    float* out = (float*)d_out;
    float* ws  = (float*)d_ws;

    float* xT    = ws + OFF_XT;
    float* mu    = ws + OFF_MU;
    float* sig   = ws + OFF_SIG;
    float* tpart = ws + OFF_TP;
    float* P     = ws + OFF_P;

    k_transpose<<<dim3(128, 8, B), dim3(32, 8), 0, stream>>>(x, xT);
    k_initmu<<<256, 256, 0, stream>>>(mu0, mu);

    // oob softmax-denominator constants: 1e-6 + oob_count/64
    // s=1: oob=0 ; s=3: 9*4096-190^2=764 ; s=5: 25*4096-314^2=3804
    const int   pvals[3]   = {0, 1, 2};
    const float dconsts[3] = {1e-6f, 1e-6f + 764.f / 64.f, 1e-6f + 3804.f / 64.f};

    for (int s = 0; s < 3; s++) {
        float* sigs = sig + (size_t)s * B * NN * K;
        for (int it = 0; it < 3; it++) {
            k_estep<<<dim3(64, B), 256, 0, stream>>>(xT, mu, sigs, pvals[s]);
            k_mstep<<<dim3(4, NCH, B), 256, 0, stream>>>(xT, sigs, tpart);
            k_norm<<<dim3(K, B), 256, 0, stream>>>(sigs, tpart, mu, dconsts[s]);
        }
        k_pmat<<<dim3(4, B), 256, 0, stream>>>(w_cat, mu, P, s);
    }
    k_final<<<dim3(64, 4, B), 256, 0, stream>>>(sig, P, x, b_cat, wsc, out);
    // append final mu to output
    hipMemcpyAsync(out + (size_t)B * C * NN, mu, (size_t)B * C * K * sizeof(float),
                   hipMemcpyDeviceToDevice, stream);
}

// Round 2
// 283.757 us; speedup vs baseline: 2.6365x; 2.6365x over previous
//
#include <hip/hip_runtime.h>

typedef float f32x4 __attribute__((ext_vector_type(4)));
typedef short bf16x8 __attribute__((ext_vector_type(8)));
typedef unsigned short u16;
typedef u16 u16x8 __attribute__((ext_vector_type(8)));

#define B 4
#define C 256
#define K 64
#define NN 4096
#define W3C 768
#define CP 264   // padded LDS row length in shorts (528B, 16B-aligned)

__device__ __forceinline__ u16 bf_hi(float f) {
    unsigned u = __float_as_uint(f);
    u += 0x7FFFu + ((u >> 16) & 1u);
    return (u16)(u >> 16);
}
__device__ __forceinline__ float bf_f(u16 s) { return __uint_as_float(((unsigned)s) << 16); }

// ---------------- prep: f32 -> bf16 hi/lo, same layout, 8 elems/thread ----------------
__global__ void k_prep8(const float* __restrict__ src, u16* __restrict__ h,
                        u16* __restrict__ l, int n8) {
    int i = blockIdx.x * 256 + threadIdx.x;
    if (i >= n8) return;
    const float4* s4 = (const float4*)(src + (size_t)i * 8);
    float4 a = s4[0], bb = s4[1];
    float v[8] = {a.x, a.y, a.z, a.w, bb.x, bb.y, bb.z, bb.w};
    u16x8 hv, lv;
    #pragma unroll
    for (int j = 0; j < 8; j++) {
        u16 hh = bf_hi(v[j]);
        hv[j] = hh;
        lv[j] = bf_hi(v[j] - bf_f(hh));
    }
    *(u16x8*)(h + (size_t)i * 8) = hv;
    *(u16x8*)(l + (size_t)i * 8) = lv;
}

// ---------------- transpose x (b,c,n) f32 -> xth/xtl (b,n,c) bf16 hi/lo ----------------
__global__ void k_prep_t(const float* __restrict__ x, u16* __restrict__ th,
                         u16* __restrict__ tl) {
    __shared__ float tile[32][33];
    int b = blockIdx.z, c0 = blockIdx.y * 32, n0 = blockIdx.x * 32;
    int tx = threadIdx.x, ty = threadIdx.y;
    #pragma unroll
    for (int j = 0; j < 4; j++)
        tile[ty + j * 8][tx] = x[((size_t)(b * C + c0 + ty + j * 8)) * NN + n0 + tx];
    __syncthreads();
    #pragma unroll
    for (int j = 0; j < 4; j++) {
        int n = n0 + ty + j * 8;
        float v = tile[tx][ty + j * 8];
        u16 hh = bf_hi(v);
        size_t o = ((size_t)(b * NN + n)) * C + c0 + tx;
        th[o] = hh;
        tl[o] = bf_hi(v - bf_f(hh));
    }
}

// ---------------- init muT (b,k,c) bf16 hi/lo from mu0 (1,c,k) ----------------
__global__ void k_initmu(const float* __restrict__ mu0, u16* __restrict__ mh,
                         u16* __restrict__ ml) {
    int k = blockIdx.x, b = blockIdx.y, c = threadIdx.x;
    float v = mu0[c * K + k];
    u16 hh = bf_hi(v);
    size_t o = ((size_t)(b * K + k)) * C + c;
    mh[o] = hh;
    ml[o] = bf_hi(v - bf_f(hh));
}

// ---------------- E-step (MFMA): logits + softmax + cnt-weight + d-partials ----------------
// grid (NN/64, B), block 256, dynamic LDS 139520 B
__global__ __launch_bounds__(256) void k_estep(
        const u16* __restrict__ xth, const u16* __restrict__ xtl,
        const u16* __restrict__ mh_g, const u16* __restrict__ ml_g,
        u16* __restrict__ sh_g, u16* __restrict__ sl_g,
        float* __restrict__ dpart, int p) {
    extern __shared__ char smem[];
    u16* sxh = (u16*)smem;                 // [64][CP] x rows n, cols c
    u16* sxl = sxh + 64 * CP;
    u16* smh = sxl + 64 * CP;              // [64][CP] muT rows k, cols c
    u16* sml = smh + 64 * CP;
    float* dred = (float*)(sml + 64 * CP); // [64][17]

    int b = blockIdx.y, ch = blockIdx.x;
    int n0 = ch * 64;
    int tid = threadIdx.x;
    size_t xbase = ((size_t)(b * NN + n0)) * C;
    size_t mbase = ((size_t)(b * K)) * C;
    for (int t = tid; t < 2048; t += 256) {
        int r = t >> 5, cof = (t & 31) * 8;
        *(u16x8*)&sxh[r * CP + cof] = *(const u16x8*)&xth[xbase + (size_t)r * C + cof];
        *(u16x8*)&sxl[r * CP + cof] = *(const u16x8*)&xtl[xbase + (size_t)r * C + cof];
        *(u16x8*)&smh[r * CP + cof] = *(const u16x8*)&mh_g[mbase + (size_t)r * C + cof];
        *(u16x8*)&sml[r * CP + cof] = *(const u16x8*)&ml_g[mbase + (size_t)r * C + cof];
    }
    __syncthreads();

    int w = tid >> 6, l = tid & 63, lg = l >> 4, lr = l & 15;
    f32x4 z4 = {0.f, 0.f, 0.f, 0.f};
    f32x4 acc[4] = {z4, z4, z4, z4};
    for (int cc = 0; cc < 8; cc++) {
        int co = cc * 32 + lg * 8;
        bf16x8 Ah = *(bf16x8*)&sxh[(w * 16 + lr) * CP + co];
        bf16x8 Al = *(bf16x8*)&sxl[(w * 16 + lr) * CP + co];
        #pragma unroll
        for (int kt = 0; kt < 4; kt++) {
            bf16x8 Bh = *(bf16x8*)&smh[(kt * 16 + lr) * CP + co];
            bf16x8 Bl = *(bf16x8*)&sml[(kt * 16 + lr) * CP + co];
            acc[kt] = __builtin_amdgcn_mfma_f32_16x16x32_bf16(Ah, Bh, acc[kt], 0, 0, 0);
            acc[kt] = __builtin_amdgcn_mfma_f32_16x16x32_bf16(Al, Bh, acc[kt], 0, 0, 0);
            acc[kt] = __builtin_amdgcn_mfma_f32_16x16x32_bf16(Ah, Bl, acc[kt], 0, 0, 0);
        }
    }

    // softmax over k: row n = n0 + w*16 + lg*4 + jj, col k = kt*16 + lr
    float psum[4] = {0.f, 0.f, 0.f, 0.f};
    #pragma unroll
    for (int jj = 0; jj < 4; jj++) {
        int n = n0 + w * 16 + lg * 4 + jj;
        float v0 = acc[0][jj], v1 = acc[1][jj], v2 = acc[2][jj], v3 = acc[3][jj];
        float m = fmaxf(fmaxf(v0, v1), fmaxf(v2, v3));
        #pragma unroll
        for (int off = 1; off <= 8; off <<= 1) m = fmaxf(m, __shfl_xor(m, off));
        float e0 = __expf(v0 - m), e1 = __expf(v1 - m), e2 = __expf(v2 - m), e3 = __expf(v3 - m);
        float s = e0 + e1 + e2 + e3;
        #pragma unroll
        for (int off = 1; off <= 8; off <<= 1) s += __shfl_xor(s, off);
        int y = n >> 6, xx = n & 63;
        float cnt = (float)((min(p, y) + min(p, 63 - y) + 1) * (min(p, xx) + min(p, 63 - xx) + 1));
        float sc = cnt / s;
        float sw[4] = {e0 * sc, e1 * sc, e2 * sc, e3 * sc};
        size_t gb = ((size_t)(b * NN + n)) * K + lr;
        #pragma unroll
        for (int kt = 0; kt < 4; kt++) {
            u16 hh = bf_hi(sw[kt]);
            sh_g[gb + kt * 16] = hh;
            sl_g[gb + kt * 16] = bf_hi(sw[kt] - bf_f(hh));
            psum[kt] += sw[kt];
        }
    }
    #pragma unroll
    for (int kt = 0; kt < 4; kt++)
        dred[(kt * 16 + lr) * 17 + w * 4 + lg] = psum[kt];
    __syncthreads();
    if (tid < 64) {
        float s = 0.f;
        #pragma unroll
        for (int g = 0; g < 16; g++) s += dred[tid * 17 + g];
        dpart[((size_t)(b * 64 + ch)) * K + tid] = s;
    }
}

// ---------------- M-step (MFMA): tpart[b][ch][k][c] over n-chunk of 256 ----------------
// grid (4, 16, B), block 256, dynamic LDS 135168 B
__global__ __launch_bounds__(256) void k_mstep(
        const u16* __restrict__ xch, const u16* __restrict__ xcl,
        const u16* __restrict__ sh_g, const u16* __restrict__ sl_g,
        float* __restrict__ tpart) {
    extern __shared__ char smem[];
    u16* ssh = (u16*)smem;          // [64][CP] sigmaT rows k, cols n
    u16* ssl = ssh + 64 * CP;
    u16* sxh = ssl + 64 * CP;       // [64][CP] x rows c, cols n
    u16* sxl = sxh + 64 * CP;
    int ct = blockIdx.x, ch = blockIdx.y, b = blockIdx.z;
    int nb = ch * 256, cb = ct * 64;
    int tid = threadIdx.x;
    // stage sigma with transpose (n,k) -> (k,n)
    for (int t = tid; t < 2048; t += 256) {
        int nl = t >> 3, kc = (t & 7) * 8;
        u16x8 vh = *(const u16x8*)&sh_g[((size_t)(b * NN + nb + nl)) * K + kc];
        u16x8 vl = *(const u16x8*)&sl_g[((size_t)(b * NN + nb + nl)) * K + kc];
        #pragma unroll
        for (int j = 0; j < 8; j++) {
            ssh[(kc + j) * CP + nl] = vh[j];
            ssl[(kc + j) * CP + nl] = vl[j];
        }
    }
    for (int t = tid; t < 2048; t += 256) {
        int r = t >> 5, nof = (t & 31) * 8;
        *(u16x8*)&sxh[r * CP + nof] = *(const u16x8*)&xch[((size_t)(b * C + cb + r)) * NN + nb + nof];
        *(u16x8*)&sxl[r * CP + nof] = *(const u16x8*)&xcl[((size_t)(b * C + cb + r)) * NN + nb + nof];
    }
    __syncthreads();

    int w = tid >> 6, l = tid & 63, lg = l >> 4, lr = l & 15;
    f32x4 z4 = {0.f, 0.f, 0.f, 0.f};
    f32x4 acc[4] = {z4, z4, z4, z4};
    for (int nn = 0; nn < 8; nn++) {
        int no = nn * 32 + lg * 8;
        bf16x8 Ah = *(bf16x8*)&ssh[(w * 16 + lr) * CP + no];
        bf16x8 Al = *(bf16x8*)&ssl[(w * 16 + lr) * CP + no];
        #pragma unroll
        for (int ci = 0; ci < 4; ci++) {
            bf16x8 Bh = *(bf16x8*)&sxh[(ci * 16 + lr) * CP + no];
            bf16x8 Bl = *(bf16x8*)&sxl[(ci * 16 + lr) * CP + no];
            acc[ci] = __builtin_amdgcn_mfma_f32_16x16x32_bf16(Ah, Bh, acc[ci], 0, 0, 0);
            acc[ci] = __builtin_amdgcn_mfma_f32_16x16x32_bf16(Al, Bh, acc[ci], 0, 0, 0);
            acc[ci] = __builtin_amdgcn_mfma_f32_16x16x32_bf16(Ah, Bl, acc[ci], 0, 0, 0);
        }
    }
    // D[k][c]: k = w*16 + lg*4 + jj, c = cb + ci*16 + lr
    #pragma unroll
    for (int ci = 0; ci < 4; ci++)
        #pragma unroll
        for (int jj = 0; jj < 4; jj++) {
            int k = w * 16 + lg * 4 + jj;
            tpart[((size_t)((b * 16 + ch) * K + k)) * C + cb + ci * 16 + lr] = acc[ci][jj];
        }
}

// ---------------- reduce + l2norm -> muT bf16 hi/lo + mu f32 ----------------
// grid (K, B), block 256 (tid = c)
__global__ void k_norm(const float* __restrict__ tpart, const float* __restrict__ dpart,
                       u16* __restrict__ mh_g, u16* __restrict__ ml_g,
                       float* __restrict__ muf, float dconst) {
    __shared__ float red[256];
    int k = blockIdx.x, b = blockIdx.y, tid = threadIdx.x;
    float dv = 0.f;
    if (tid < 64) dv = dpart[((size_t)(b * 64 + tid)) * K + k];
    red[tid] = dv; __syncthreads();
    for (int s = 128; s > 0; s >>= 1) { if (tid < s) red[tid] += red[tid + s]; __syncthreads(); }
    float d = dconst + red[0];
    __syncthreads();
    float tt = 0.f;
    #pragma unroll
    for (int chn = 0; chn < 16; chn++)
        tt += tpart[((size_t)((b * 16 + chn) * K + k)) * C + tid];
    red[tid] = tt * tt; __syncthreads();
    for (int s = 128; s > 0; s >>= 1) { if (tid < s) red[tid] += red[tid + s]; __syncthreads(); }
    float inv = 1.f / (1e-6f * d + sqrtf(red[0]));
    float v = tt * inv;
    size_t o = ((size_t)(b * K + k)) * C + tid;
    u16 hh = bf_hi(v);
    mh_g[o] = hh;
    ml_g[o] = bf_hi(v - bf_f(hh));
    muf[((size_t)(b * C + tid)) * K + k] = v;
}

// ---------------- P (MFMA): Pb[s][b][o][k] bf16 = sum_c w_cat[o][sC+c] mu[c][k] ----------------
// grid (4, B), block 256
__global__ __launch_bounds__(256) void k_pmat(
        const u16* __restrict__ wch, const u16* __restrict__ wcl,
        const u16* __restrict__ mh_g, const u16* __restrict__ ml_g,
        u16* __restrict__ Pb, int s) {
    int ob = blockIdx.x, b = blockIdx.y;
    int tid = threadIdx.x, w = tid >> 6, l = tid & 63, lg = l >> 4, lr = l & 15;
    f32x4 z4 = {0.f, 0.f, 0.f, 0.f};
    f32x4 acc[4] = {z4, z4, z4, z4};
    int orow = ob * 64 + w * 16 + lr;
    const u16* wbh = wch + (size_t)orow * W3C + s * C;
    const u16* wbl = wcl + (size_t)orow * W3C + s * C;
    for (int cc = 0; cc < 8; cc++) {
        int co = cc * 32 + lg * 8;
        bf16x8 Ah = *(const bf16x8*)&wbh[co];
        bf16x8 Al = *(const bf16x8*)&wbl[co];
        #pragma unroll
        for (int kt = 0; kt < 4; kt++) {
            bf16x8 Bh = *(const bf16x8*)&mh_g[((size_t)(b * K + kt * 16 + lr)) * C + co];
            bf16x8 Bl = *(const bf16x8*)&ml_g[((size_t)(b * K + kt * 16 + lr)) * C + co];
            acc[kt] = __builtin_amdgcn_mfma_f32_16x16x32_bf16(Ah, Bh, acc[kt], 0, 0, 0);
            acc[kt] = __builtin_amdgcn_mfma_f32_16x16x32_bf16(Al, Bh, acc[kt], 0, 0, 0);
            acc[kt] = __builtin_amdgcn_mfma_f32_16x16x32_bf16(Ah, Bl, acc[kt], 0, 0, 0);
        }
    }
    #pragma unroll
    for (int kt = 0; kt < 4; kt++)
        #pragma unroll
        for (int jj = 0; jj < 4; jj++) {
            int o = ob * 64 + w * 16 + lg * 4 + jj;
            Pb[((size_t)((s * B + b) * C + o)) * K + kt * 16 + lr] = bf_hi(acc[kt][jj]);
        }
}

// ---------------- final (MFMA): out = relu(w*(sum_s sig_s P_s^T + b_cat) + x) ----------------
// grid (NN/64, C/64, B), block 256
__global__ __launch_bounds__(256) void k_final(
        const u16* __restrict__ sh_g, const u16* __restrict__ Pb,
        const float* __restrict__ x, const float* __restrict__ b_cat,
        const float* __restrict__ wscal, float* __restrict__ out) {
    __shared__ u16 ssig[64 * 72];
    __shared__ u16 sP[64 * 72];
    __shared__ float tbuf[64 * 68];
    int nt = blockIdx.x, ot = blockIdx.y, b = blockIdx.z;
    int n0 = nt * 64, o0 = ot * 64;
    int tid = threadIdx.x, w = tid >> 6, l = tid & 63, lg = l >> 4, lr = l & 15;
    f32x4 z4 = {0.f, 0.f, 0.f, 0.f};
    f32x4 acc[4] = {z4, z4, z4, z4};
    for (int s = 0; s < 3; s++) {
        __syncthreads();
        for (int t = tid; t < 512; t += 256) {
            int r = t >> 3, kc = (t & 7) * 8;
            *(u16x8*)&ssig[r * 72 + kc] =
                *(const u16x8*)&sh_g[(size_t)s * ((size_t)B * NN * K) + ((size_t)(b * NN + n0 + r)) * K + kc];
            *(u16x8*)&sP[r * 72 + kc] =
                *(const u16x8*)&Pb[((size_t)((s * B + b) * C + o0 + r)) * K + kc];
        }
        __syncthreads();
        #pragma unroll
        for (int kk = 0; kk < 2; kk++) {
            int ko = kk * 32 + lg * 8;
            bf16x8 A = *(bf16x8*)&ssig[(w * 16 + lr) * 72 + ko];
            #pragma unroll
            for (int oi = 0; oi < 4; oi++) {
                bf16x8 Bv = *(bf16x8*)&sP[(oi * 16 + lr) * 72 + ko];
                acc[oi] = __builtin_amdgcn_mfma_f32_16x16x32_bf16(A, Bv, acc[oi], 0, 0, 0);
            }
        }
    }
    __syncthreads();
    #pragma unroll
    for (int oi = 0; oi < 4; oi++)
        #pragma unroll
        for (int jj = 0; jj < 4; jj++)
            tbuf[(oi * 16 + lr) * 68 + (w * 16 + lg * 4 + jj)] = acc[oi][jj];
    __syncthreads();
    float wv = wscal[0];
    for (int t = tid; t < 1024; t += 256) {
        int ol = t >> 4, ck = (t & 15) * 4;
        int o = o0 + ol;
        float bc = b_cat[o];
        float4 u4 = *(float4*)&tbuf[ol * 68 + ck];
        size_t base = ((size_t)(b * C + o)) * NN + n0 + ck;
        float4 xv = *(const float4*)&x[base];
        float4 r;
        r.x = fmaxf((u4.x + bc) * wv + xv.x, 0.f);
        r.y = fmaxf((u4.y + bc) * wv + xv.y, 0.f);
        r.z = fmaxf((u4.z + bc) * wv + xv.z, 0.f);
        r.w = fmaxf((u4.w + bc) * wv + xv.w, 0.f);
        *(float4*)&out[base] = r;
    }
}

extern "C" void kernel_launch(void* const* d_in, const int* in_sizes, int n_in,
                              void* d_out, int out_size, void* d_ws, size_t ws_size,
                              hipStream_t stream) {
    const float* x     = (const float*)d_in[0];
    const float* mu0   = (const float*)d_in[1];
    const float* wsc   = (const float*)d_in[2];
    const float* w_cat = (const float*)d_in[3];
    const float* b_cat = (const float*)d_in[4];
    float* out = (float*)d_out;
    char* wsb = (char*)d_ws;

    const size_t SZ_XT = (size_t)B * NN * C * 2;          // 8,388,608
    u16* xth  = (u16*)(wsb);
    u16* xtl  = (u16*)(wsb + SZ_XT);
    u16* xch  = (u16*)(wsb + 2 * SZ_XT);
    u16* xcl  = (u16*)(wsb + 3 * SZ_XT);
    u16* muth = (u16*)(wsb + 4 * SZ_XT);                  // 131072 B
    u16* mutl = (u16*)(wsb + 4 * SZ_XT + 131072);
    u16* sigh = (u16*)(wsb + 4 * SZ_XT + 262144);         // 3 * 2 MB
    u16* sigl = (u16*)(wsb + 4 * SZ_XT + 262144 + 6291456);
    float* tpart = (float*)(wsb + 4 * SZ_XT + 262144 + 8388608);   // 4 MB
    float* dpart = (float*)((char*)tpart + 4194304);               // 64 KB
    u16*   Pb    = (u16*)((char*)dpart + 65536);                   // 384 KB
    float* muf   = (float*)((char*)Pb + 393216);                   // 256 KB
    u16*   wch   = (u16*)((char*)muf + 262144);                    // 384 KB
    u16*   wcl   = wch + (size_t)C * W3C;

    const int ESTEP_LDS = 4 * 64 * CP * 2 + 64 * 17 * 4;  // 139,520
    const int MSTEP_LDS = 4 * 64 * CP * 2;                // 135,168
    hipFuncSetAttribute((const void*)k_estep, hipFuncAttributeMaxDynamicSharedMemorySize, ESTEP_LDS);
    hipFuncSetAttribute((const void*)k_mstep, hipFuncAttributeMaxDynamicSharedMemorySize, MSTEP_LDS);

    k_prep8<<<2048, 256, 0, stream>>>(x, xch, xcl, B * C * NN / 8);
    k_prep_t<<<dim3(128, 8, B), dim3(32, 8), 0, stream>>>(x, xth, xtl);
    k_prep8<<<96, 256, 0, stream>>>(w_cat, wch, wcl, C * W3C / 8);
    k_initmu<<<dim3(K, B), 256, 0, stream>>>(mu0, muth, mutl);

    const int   pvals[3]   = {0, 1, 2};
    const float dconsts[3] = {1e-6f, 1e-6f + 764.f / 64.f, 1e-6f + 3804.f / 64.f};

    for (int s = 0; s < 3; s++) {
        u16* shs = sigh + (size_t)s * B * NN * K;
        for (int it = 0; it < 3; it++) {
            k_estep<<<dim3(64, B), 256, ESTEP_LDS, stream>>>(xth, xtl, muth, mutl,
                                                             shs, sigl, dpart, pvals[s]);
            k_mstep<<<dim3(4, 16, B), 256, MSTEP_LDS, stream>>>(xch, xcl, shs, sigl, tpart);
            k_norm<<<dim3(K, B), 256, 0, stream>>>(tpart, dpart, muth, mutl, muf, dconsts[s]);
        }
        k_pmat<<<dim3(4, B), 256, 0, stream>>>(wch, wcl, muth, mutl, Pb, s);
    }
    k_final<<<dim3(64, 4, B), 256, 0, stream>>>(sigh, Pb, x, b_cat, wsc, out);
    hipMemcpyAsync(out + (size_t)B * C * NN, muf, (size_t)B * C * K * sizeof(float),
                   hipMemcpyDeviceToDevice, stream);
}